// Round 3
// baseline (464.033 us; speedup 1.0000x reference)
//
#include <hip/hip_runtime.h>

#define Tsz 512
#define Hsz 256

typedef __attribute__((ext_vector_type(8))) short short8;
typedef __attribute__((ext_vector_type(4))) float f32x4;

static __device__ __forceinline__ float bf2f(unsigned short u) {
    union { unsigned int i; float f; } v; v.i = ((unsigned int)u) << 16; return v.f;
}
static __device__ __forceinline__ unsigned short f2bf(float f) {
    union { float f; unsigned int i; } v; v.f = f;
    unsigned int r = v.i + 0x7fffu + ((v.i >> 16) & 1u);   // RNE
    return (unsigned short)(r >> 16);
}
// load 8 consecutive f32, round to bf16x8
static __device__ __forceinline__ short8 ld8f(const float* p) {
    const float4* q = (const float4*)p;
    float4 a = q[0], b = q[1];
    short8 v;
    v[0] = (short)f2bf(a.x); v[1] = (short)f2bf(a.y); v[2] = (short)f2bf(a.z); v[3] = (short)f2bf(a.w);
    v[4] = (short)f2bf(b.x); v[5] = (short)f2bf(b.y); v[6] = (short)f2bf(b.z); v[7] = (short)f2bf(b.w);
    return v;
}
static __device__ __forceinline__ float sigm(float z) {
    return __builtin_amdgcn_rcpf(1.f + __expf(-z));
}

// Fused MGU: gates chunked 16-t at full MFMA M-efficiency + sequential h scan.
// 256 blocks (1 batch each), 256 threads (4 waves), Wh+Wx frags in registers.
__global__ __launch_bounds__(256, 1) void mgu_fused(
    const float* __restrict__ x,   const float* __restrict__ Wxw,
    const float* __restrict__ Wxb, const float* __restrict__ Whw,
    const float* __restrict__ Whb, float* __restrict__ out)
{
    __shared__ __align__(16) unsigned short xs[2][16 * 256];  // bf16 x chunks (swizzled)
    __shared__ __align__(16) float          gs[2][16 * 256];  // f32 gates
    __shared__ __align__(16) unsigned short hbuf[2][256];     // bf16 h double buffer

    const int tid  = threadIdx.x;
    const int b    = blockIdx.x;
    const int l    = tid & 63;
    const int w    = tid >> 6;
    const int lo16 = l & 15;
    const int hi   = l >> 4;

    // Resident weight fragments: B[k][n] = W[n][k]; lane n = w*64+nt*16+lo16,
    // k = ks*32 + hi*8 .. +7  (same mapping as verified round-2 kernel)
    short8 wfh[4][8], wfx[4][8];
    float  bh[4], bx[4];
#pragma unroll
    for (int nt = 0; nt < 4; ++nt) {
        int n = w * 64 + nt * 16 + lo16;
        bh[nt] = Whb[n];
        bx[nt] = Wxb[n];
#pragma unroll
        for (int ks = 0; ks < 8; ++ks) {
            wfh[nt][ks] = ld8f(Whw + (size_t)n * 256 + ks * 32 + hi * 8);
            wfx[nt][ks] = ld8f(Wxw + (size_t)n * 256 + ks * 32 + hi * 8);
        }
    }

    const float* xrow = x   + (size_t)b * Tsz * Hsz;
    float*       orow = out + (size_t)b * Tsz * Hsz;

    // ---- prologue: stage x chunks 0,1 (swizzled bf16) ----
#pragma unroll
    for (int m = 0; m < 16; ++m) {
        unsigned short v0 = f2bf(xrow[(size_t)m * 256 + tid]);
        unsigned short v1 = f2bf(xrow[(size_t)(16 + m) * 256 + tid]);
        int byt = m * 512 + (((tid >> 3) ^ (m & 7)) << 4) + (tid & 7) * 2;
        *(unsigned short*)((char*)xs[0] + byt) = v0;
        *(unsigned short*)((char*)xs[1] + byt) = v1;
    }
    hbuf[0][tid] = 0;
    __syncthreads();

    // gates chunk 0 -> gs[0] (full 32-MFMA pass)
    {
        f32x4 ag[4];
#pragma unroll
        for (int nt = 0; nt < 4; ++nt) { f32x4 z = {0.f, 0.f, 0.f, 0.f}; ag[nt] = z; }
#pragma unroll
        for (int ks = 0; ks < 8; ++ks) {
            short8 afg = *(const short8*)((const char*)xs[0]
                           + lo16 * 512 + (((ks * 4 + hi) ^ (lo16 & 7)) << 4));
#pragma unroll
            for (int nt = 0; nt < 4; ++nt)
                ag[nt] = __builtin_amdgcn_mfma_f32_16x16x32_bf16(afg, wfx[nt][ks], ag[nt], 0, 0, 0);
        }
#pragma unroll
        for (int nt = 0; nt < 4; ++nt)
#pragma unroll
            for (int r = 0; r < 4; ++r)
                gs[0][(hi * 4 + r) * 256 + w * 64 + nt * 16 + lo16] = sigm(ag[nt][r] + bx[nt]);
    }

    float hreg = 0.f;
    float xcarry = xrow[(size_t)32 * 256 + tid];   // x row t+32 for first stage-write
    int   p = 0;
    f32x4 accg[4];
#pragma unroll
    for (int nt = 0; nt < 4; ++nt) { f32x4 z = {0.f, 0.f, 0.f, 0.f}; accg[nt] = z; }

    for (int c = 0; c < 32; ++c) {
        unsigned short* xs_rd = xs[(c & 1) ^ 1];   // x of chunk c+1 (gate drip source)
        unsigned short* xs_wr = xs[c & 1];         // staging x of chunk c+2
        const float*    gs_rd = gs[c & 1];         // gates of chunk c
        float*          gs_wr = gs[(c & 1) ^ 1];   // gates of chunk c+1 (epilogue @ s=15)
        short8 afg;
#pragma unroll
        for (int s = 0; s < 16; ++s) {
            const int t = c * 16 + s;
            __syncthreads();                        // h[t-1], gates, staged x visible

            float g = gs_rd[s * 256 + tid];

            // A fragments from h broadcast
            short8 afh[8];
#pragma unroll
            for (int ks = 0; ks < 8; ++ks)
                afh[ks] = *(const short8*)(const void*)(&hbuf[p][ks * 32 + hi * 8]);

            // h-matvec (critical): 32 MFMAs, 4 independent acc chains
            f32x4 acc[4];
#pragma unroll
            for (int nt = 0; nt < 4; ++nt) { f32x4 z = {bh[nt], 0.f, 0.f, 0.f}; acc[nt] = z; }
#pragma unroll
            for (int ks = 0; ks < 8; ++ks)
#pragma unroll
                for (int nt = 0; nt < 4; ++nt)
                    acc[nt] = __builtin_amdgcn_mfma_f32_16x16x32_bf16(afh[ks], wfh[nt][ks], acc[nt], 0, 0, 0);

            // gate drip for chunk c+1: 2 MFMAs/step (ks = s>>1, nts {2s&3, 2s+1&3})
            if ((s & 1) == 0)
                afg = *(const short8*)((const char*)xs_rd
                        + lo16 * 512 + ((((s >> 1) * 4 + hi) ^ (lo16 & 7)) << 4));
            {
                const int i0 = (2 * s) & 3, i1 = (2 * s + 1) & 3, ksg = s >> 1;
                accg[i0] = __builtin_amdgcn_mfma_f32_16x16x32_bf16(afg, wfx[i0][ksg], accg[i0], 0, 0, 0);
                accg[i1] = __builtin_amdgcn_mfma_f32_16x16x32_bf16(afg, wfx[i1][ksg], accg[i1], 0, 0, 0);
            }

            // h epilogue: acc[nt][0] with nt=hi gives column n == tid
            float zz = (hi == 0) ? acc[0][0] : ((hi == 1) ? acc[1][0]
                       : ((hi == 2) ? acc[2][0] : acc[3][0]));
            zz = fminf(fmaxf(zz, -15.f), 15.f);
            float ex = __expf(2.f * zz);
            float th = (ex - 1.f) * __builtin_amdgcn_rcpf(ex + 1.f);
            float hn = g * hreg + (1.f - g) * th;

            hreg = hn;
            hbuf[p ^ 1][tid] = f2bf(hn);
            orow[(size_t)t * 256 + tid] = hn;

            // stage x (chunk c+2, row s) from carry; refill carry (row t+33)
            {
                int byt = s * 512 + (((tid >> 3) ^ (s & 7)) << 4) + (tid & 7) * 2;
                *(unsigned short*)((char*)xs_wr + byt) = f2bf(xcarry);
            }
            {
                int nr = t + 33; if (nr > Tsz - 1) nr = Tsz - 1;
                xcarry = xrow[(size_t)nr * 256 + tid];
            }

            if (s == 15) {   // finish gates chunk c+1
#pragma unroll
                for (int nt = 0; nt < 4; ++nt) {
#pragma unroll
                    for (int r = 0; r < 4; ++r)
                        gs_wr[(hi * 4 + r) * 256 + w * 64 + nt * 16 + lo16]
                            = sigm(accg[nt][r] + bx[nt]);
                    f32x4 z = {0.f, 0.f, 0.f, 0.f}; accg[nt] = z;
                }
            }
            p ^= 1;
        }
    }
}

extern "C" void kernel_launch(void* const* d_in, const int* in_sizes, int n_in,
                              void* d_out, int out_size, void* d_ws, size_t ws_size,
                              hipStream_t stream) {
    const float* x   = (const float*)d_in[0];
    const float* Wxw = (const float*)d_in[1];
    const float* Wxb = (const float*)d_in[2];
    const float* Whw = (const float*)d_in[3];
    const float* Whb = (const float*)d_in[4];

    mgu_fused<<<dim3(256), dim3(256), 0, stream>>>(x, Wxw, Wxb, Whw, Whb, (float*)d_out);
}

// Round 4
// 272.891 us; speedup vs baseline: 1.7004x; 1.7004x over previous
//
#include <hip/hip_runtime.h>

#define Tsz 512
#define Hsz 256

typedef __attribute__((ext_vector_type(8))) short short8;
typedef __attribute__((ext_vector_type(4))) short short4v;
typedef __attribute__((ext_vector_type(4))) float f32x4;

static __device__ __forceinline__ unsigned short f2bf(float f) {
    union { float f; unsigned int i; } v; v.f = f;
    unsigned int r = v.i + 0x7fffu + ((v.i >> 16) & 1u);   // RNE
    return (unsigned short)(r >> 16);
}
static __device__ __forceinline__ short8 ld8f(const float* p) {
    const float4* q = (const float4*)p;
    float4 a = q[0], b = q[1];
    short8 v;
    v[0] = (short)f2bf(a.x); v[1] = (short)f2bf(a.y); v[2] = (short)f2bf(a.z); v[3] = (short)f2bf(a.w);
    v[4] = (short)f2bf(b.x); v[5] = (short)f2bf(b.y); v[6] = (short)f2bf(b.z); v[7] = (short)f2bf(b.w);
    return v;
}
static __device__ __forceinline__ float sigm(float z) {
    return __builtin_amdgcn_rcpf(1.f + __expf(-z));
}

// Fused MGU, 8 waves/block, 1 block/CU. Wave w owns output cols [w*32, w*32+32).
// Weights (Wh+Wx) register-resident as MFMA B-frags: 2 nt-tiles x 8 ks = 128 VGPR.
__global__ __launch_bounds__(512, 1) void mgu_fused(
    const float* __restrict__ x,   const float* __restrict__ Wxw,
    const float* __restrict__ Wxb, const float* __restrict__ Whw,
    const float* __restrict__ Whb, float* __restrict__ out)
{
    __shared__ __align__(16) unsigned short xs[2][16 * 256];  // bf16 x chunks, swizzled (16 KB)
    __shared__ __align__(16) float          gs[2][16 * 256];  // f32 gates (32 KB)
    __shared__ __align__(16) unsigned short hbuf[2][256];     // bf16 h double buffer (1 KB)

    const int tid  = threadIdx.x;
    const int b    = blockIdx.x;
    const int l    = tid & 63;
    const int w    = tid >> 6;       // 0..7
    const int lo16 = l & 15;
    const int hi   = l >> 4;

    // B-frags: B[k][n] = W[n][k]; lane holds n = w*32+nt*16+lo16, k = ks*32+hi*8..+7
    short8 wfh[2][8], wfx[2][8];
    float  bh[2], bx[2];
#pragma unroll
    for (int nt = 0; nt < 2; ++nt) {
        int n = w * 32 + nt * 16 + lo16;
        bh[nt] = Whb[n];
        bx[nt] = Wxb[n];
#pragma unroll
        for (int ks = 0; ks < 8; ++ks) {
            wfh[nt][ks] = ld8f(Whw + (size_t)n * 256 + ks * 32 + hi * 8);
            wfx[nt][ks] = ld8f(Wxw + (size_t)n * 256 + ks * 32 + hi * 8);
        }
    }

    const float* xrow = x   + (size_t)b * Tsz * Hsz;
    float*       orow = out + (size_t)b * Tsz * Hsz;

    // ---- prologue: stage x chunks 0,1 (bf16, 16B-chunk XOR swizzle) ----
#pragma unroll
    for (int i = 0; i < 4; ++i) {
        int idx = tid + i * 512;          // 0..2047
        int m   = idx >> 6;               // global row 0..31
        int j   = idx & 63;               // float4 index in row
        float4 v = *(const float4*)(xrow + (size_t)m * 256 + j * 4);
        short4v s4;
        s4[0] = (short)f2bf(v.x); s4[1] = (short)f2bf(v.y);
        s4[2] = (short)f2bf(v.z); s4[3] = (short)f2bf(v.w);
        int r   = m & 15;
        int byt = r * 512 + (((j >> 1) ^ (r & 7)) << 4) + (j & 1) * 8;
        *(short4v*)((char*)xs[m >> 4] + byt) = s4;
    }
    if (tid < 256) hbuf[0][tid] = 0;
    __syncthreads();

    // ---- gates chunk 0 (full pass: 16 MFMAs/wave) ----
    {
        f32x4 ag0 = {0.f, 0.f, 0.f, 0.f}, ag1 = {0.f, 0.f, 0.f, 0.f};
#pragma unroll
        for (int ks = 0; ks < 8; ++ks) {
            short8 afg = *(const short8*)((const char*)xs[0]
                           + lo16 * 512 + (((ks * 4 + hi) ^ (lo16 & 7)) << 4));
            ag0 = __builtin_amdgcn_mfma_f32_16x16x32_bf16(afg, wfx[0][ks], ag0, 0, 0, 0);
            ag1 = __builtin_amdgcn_mfma_f32_16x16x32_bf16(afg, wfx[1][ks], ag1, 0, 0, 0);
        }
#pragma unroll
        for (int r = 0; r < 4; ++r) {
            gs[0][(hi * 4 + r) * 256 + w * 32 + lo16]      = sigm(ag0[r] + bx[0]);
            gs[0][(hi * 4 + r) * 256 + w * 32 + 16 + lo16] = sigm(ag1[r] + bx[1]);
        }
    }

    float  hreg = 0.f;
    float4 xcarry;
    if (tid < 64) xcarry = *(const float4*)(xrow + (size_t)32 * 256 + tid * 4);

    f32x4 accg[2];
    { f32x4 z = {0.f, 0.f, 0.f, 0.f}; accg[0] = z; accg[1] = z; }

    int p = 0;
    for (int c = 0; c < 32; ++c) {
        unsigned short* xs_rd = xs[(c & 1) ^ 1];   // x of chunk c+1 (drip source)
        unsigned short* xs_wr = xs[c & 1];         // staging x of chunk c+2
        const float*    gs_rd = gs[c & 1];         // gates of chunk c
        float*          gs_wr = gs[(c & 1) ^ 1];   // gates of chunk c+1
        short8 afg;
#pragma unroll
        for (int s = 0; s < 16; ++s) {
            const int t = c * 16 + s;
            __syncthreads();                        // h[t-1], gates, staged x visible

            // A frags from h broadcast (16 identical rows)
            short8 afh[8];
#pragma unroll
            for (int ks = 0; ks < 8; ++ks)
                afh[ks] = *(const short8*)(const void*)(&hbuf[p][ks * 32 + hi * 8]);

            // h-matvec: 16 MFMAs/wave, 4 independent chains of 4 (split-K)
            f32x4 a0lo = {bh[0], 0.f, 0.f, 0.f}, a0hi = {0.f, 0.f, 0.f, 0.f};
            f32x4 a1lo = {bh[1], 0.f, 0.f, 0.f}, a1hi = {0.f, 0.f, 0.f, 0.f};
#pragma unroll
            for (int ks = 0; ks < 4; ++ks) {
                a0lo = __builtin_amdgcn_mfma_f32_16x16x32_bf16(afh[ks],     wfh[0][ks],     a0lo, 0, 0, 0);
                a1lo = __builtin_amdgcn_mfma_f32_16x16x32_bf16(afh[ks],     wfh[1][ks],     a1lo, 0, 0, 0);
                a0hi = __builtin_amdgcn_mfma_f32_16x16x32_bf16(afh[ks + 4], wfh[0][ks + 4], a0hi, 0, 0, 0);
                a1hi = __builtin_amdgcn_mfma_f32_16x16x32_bf16(afh[ks + 4], wfh[1][ks + 4], a1hi, 0, 0, 0);
            }

            // gate drip for chunk c+1: 1 MFMA/step (nt = s&1, ks = s>>1)
            if ((s & 1) == 0)
                afg = *(const short8*)((const char*)xs_rd
                        + lo16 * 512 + ((((s >> 1) * 4 + hi) ^ (lo16 & 7)) << 4));
            accg[s & 1] = __builtin_amdgcn_mfma_f32_16x16x32_bf16(afg, wfx[s & 1][s >> 1], accg[s & 1], 0, 0, 0);

            // stage x row t+32 (chunk c+2, row s): 64 threads, b64 writes
            if (tid < 64) {
                short4v s4;
                s4[0] = (short)f2bf(xcarry.x); s4[1] = (short)f2bf(xcarry.y);
                s4[2] = (short)f2bf(xcarry.z); s4[3] = (short)f2bf(xcarry.w);
                int byt = s * 512 + (((tid >> 1) ^ (s & 7)) << 4) + (tid & 1) * 8;
                *(short4v*)((char*)xs_wr + byt) = s4;
                int nr = t + 33; if (nr > Tsz - 1) nr = Tsz - 1;
                xcarry = *(const float4*)(xrow + (size_t)nr * 256 + tid * 4);
            }

            // epilogue: col n = w*32 + hi*16 + lo16 owned by hi<2 threads
            float zz = (hi == 0) ? (a0lo[0] + a0hi[0]) : (a1lo[0] + a1hi[0]);
            zz = fminf(fmaxf(zz, -15.f), 15.f);
            float ex = __expf(2.f * zz);
            float th = (ex - 1.f) * __builtin_amdgcn_rcpf(ex + 1.f);
            if (hi < 2) {
                int   n  = w * 32 + hi * 16 + lo16;
                float g  = gs_rd[s * 256 + n];
                float hn = g * hreg + (1.f - g) * th;
                hreg = hn;
                hbuf[p ^ 1][n] = f2bf(hn);
                orow[(size_t)t * 256 + n] = hn;
            }

            if (s == 15) {   // finish gates chunk c+1
#pragma unroll
                for (int r = 0; r < 4; ++r) {
                    gs_wr[(hi * 4 + r) * 256 + w * 32 + lo16]      = sigm(accg[0][r] + bx[0]);
                    gs_wr[(hi * 4 + r) * 256 + w * 32 + 16 + lo16] = sigm(accg[1][r] + bx[1]);
                }
                f32x4 z = {0.f, 0.f, 0.f, 0.f}; accg[0] = z; accg[1] = z;
            }
            p ^= 1;
        }
    }
}

extern "C" void kernel_launch(void* const* d_in, const int* in_sizes, int n_in,
                              void* d_out, int out_size, void* d_ws, size_t ws_size,
                              hipStream_t stream) {
    const float* x   = (const float*)d_in[0];
    const float* Wxw = (const float*)d_in[1];
    const float* Wxb = (const float*)d_in[2];
    const float* Whw = (const float*)d_in[3];
    const float* Whb = (const float*)d_in[4];

    mgu_fused<<<dim3(256), dim3(512), 0, stream>>>(x, Wxw, Wxb, Whw, Whb, (float*)d_out);
}